// Round 4
// baseline (561.952 us; speedup 1.0000x reference)
//
#include <hip/hip_runtime.h>
#include <stdint.h>

// Problem constants: grid (1, C=12, D=160, H=160, W=160), N = 2e6 points.
#define CC 12
#define DD 160
#define HH 160
#define WW 160

static constexpr int    HWi        = HH * WW;                 // 25600
static constexpr int    DHWi       = DD * HH * WW;            // 4,096,000
static constexpr size_t GT24_BYTES = (size_t)DHWi * 24;       // 98,304,000  (bf16 DHWC, 24B/cell)
static constexpr size_t GT32_BYTES = (size_t)DHWi * 32;       // 131,072,000 (bf16 DHWC, padded 32B/cell)

typedef float f32x4 __attribute__((ext_vector_type(4)));      // native vector: OK for nontemporal builtins

// ---- bf16 helpers (RNE) ----
__device__ __forceinline__ uint32_t pack_bf16(float a, float b) {
    uint32_t ua = __float_as_uint(a);
    uint32_t ub = __float_as_uint(b);
    uint32_t ra = (ua + 0x7fffu + ((ua >> 16) & 1u)) >> 16;
    uint32_t rb = (ub + 0x7fffu + ((ub >> 16) & 1u)) >> 16;
    return (ra & 0xffffu) | (rb << 16);
}
__device__ __forceinline__ float bf_lo(uint32_t q) { return __uint_as_float(q << 16); }
__device__ __forceinline__ float bf_hi(uint32_t q) { return __uint_as_float(q & 0xffff0000u); }

// Shared coordinate math: u = clip((p-min)/(max-min)*(size-1)), i0 = clip(floor(u), 0, size-2)
__device__ __forceinline__ void coord(float p, float mn, float mx, int& i0, float& f) {
    float u = (p - mn) / (mx - mn) * 159.0f;
    u = fminf(fmaxf(u, 0.0f), 159.0f);
    float i0f = fminf(floorf(u), 158.0f);
    f = u - i0f;
    i0 = (int)i0f;
}

// ======================= Padded-32B path (preferred) =======================
// (C,D,H,W) fp32 -> (D,H,W,16ch) bf16, 32B per cell (12 real channels + pad).
__global__ __launch_bounds__(256) void transpose_pad32(
    const float* __restrict__ g, uint4* __restrict__ gt) {
    int idx = blockIdx.x * 256 + threadIdx.x;
    if (idx >= DHWi) return;
    uint32_t q[6];
#pragma unroll
    for (int j = 0; j < 6; ++j) {
        float a = __builtin_nontemporal_load(g + (size_t)(2 * j) * DHWi + idx);
        float b = __builtin_nontemporal_load(g + (size_t)(2 * j + 1) * DHWi + idx);
        q[j] = pack_bf16(a, b);          // dword j = channels 2j (lo), 2j+1 (hi)
    }
    gt[(size_t)idx * 2 + 0] = make_uint4(q[0], q[1], q[2], q[3]);
    gt[(size_t)idx * 2 + 1] = make_uint4(q[4], q[5], 0u, 0u);
}

// Gather: per point, 4 segments of 64B (w0,w0+1 cells), each 32B-aligned ->
// 4x dwordx4 per segment = 16 aligned 16B gathers per point (was 24x 8B).
__global__ __launch_bounds__(256, 4) void trilerp_pad32(
    const float* __restrict__ xyz, const uint4* __restrict__ gt,
    const float* __restrict__ xyz_min, const float* __restrict__ xyz_max,
    float* __restrict__ out, int n) {
    int i = blockIdx.x * 256 + threadIdx.x;
    if (i >= n) return;

    float px = __builtin_nontemporal_load(xyz + 3 * (size_t)i + 0);
    float py = __builtin_nontemporal_load(xyz + 3 * (size_t)i + 1);
    float pz = __builtin_nontemporal_load(xyz + 3 * (size_t)i + 2);

    int d0, h0, w0; float fd, fh, fw;
    coord(px, xyz_min[0], xyz_max[0], d0, fd);
    coord(py, xyz_min[1], xyz_max[1], h0, fh);
    coord(pz, xyz_min[2], xyz_max[2], w0, fw);

    const uint4* base = gt + ((size_t)(d0 * HH + h0) * WW + w0) * 2;
    const size_t sD = (size_t)HWi * 2;   // d-stride in uint4
    const size_t sH = (size_t)WW * 2;    // h-stride in uint4

    // Issue all 16 gather loads first (maximize MLP), then interpolate.
    uint4 s[4][4];
#pragma unroll
    for (int dd = 0; dd < 2; ++dd) {
#pragma unroll
        for (int hh = 0; hh < 2; ++hh) {
            const uint4* p = base + dd * sD + hh * sH;
            int k = dd * 2 + hh;
            s[k][0] = p[0];   // cell w0 : ch 0..7
            s[k][1] = p[1];   // cell w0 : ch 8..11 + pad
            s[k][2] = p[2];   // cell w1 : ch 0..7
            s[k][3] = p[3];   // cell w1 : ch 8..11 + pad
        }
    }

    float acc[12];
#pragma unroll
    for (int c = 0; c < 12; ++c) acc[c] = 0.0f;
    float wd[2] = {1.0f - fd, fd};
    float wh[2] = {1.0f - fh, fh};

#pragma unroll
    for (int dd = 0; dd < 2; ++dd) {
#pragma unroll
        for (int hh = 0; hh < 2; ++hh) {
            int k = dd * 2 + hh;
            float wdh = wd[dd] * wh[hh];
            uint32_t qa[6] = {s[k][0].x, s[k][0].y, s[k][0].z, s[k][0].w, s[k][1].x, s[k][1].y};
            uint32_t qb[6] = {s[k][2].x, s[k][2].y, s[k][2].z, s[k][2].w, s[k][3].x, s[k][3].y};
#pragma unroll
            for (int j = 0; j < 6; ++j) {
                float v0l = bf_lo(qa[j]), v0h = bf_hi(qa[j]);
                float v1l = bf_lo(qb[j]), v1h = bf_hi(qb[j]);
                float tl = fmaf(fw, v1l - v0l, v0l);
                float th = fmaf(fw, v1h - v0h, v0h);
                acc[2 * j]     = fmaf(wdh, tl, acc[2 * j]);
                acc[2 * j + 1] = fmaf(wdh, th, acc[2 * j + 1]);
            }
        }
    }

    float* o = out + (size_t)i * 12;
    f32x4 o0 = {acc[0], acc[1], acc[2],  acc[3]};
    f32x4 o1 = {acc[4], acc[5], acc[6],  acc[7]};
    f32x4 o2 = {acc[8], acc[9], acc[10], acc[11]};
    __builtin_nontemporal_store(o0, (f32x4*)(o + 0));
    __builtin_nontemporal_store(o1, (f32x4*)(o + 4));
    __builtin_nontemporal_store(o2, (f32x4*)(o + 8));
}

// ======================= 24B path (ws fallback, round-1 kernel) =======================
__global__ __launch_bounds__(256) void transpose_to_bf16(
    const float* __restrict__ g, uint32_t* __restrict__ gt) {
    int idx = blockIdx.x * 256 + threadIdx.x;
    if (idx >= DHWi) return;
    uint32_t q[6];
#pragma unroll
    for (int j = 0; j < 6; ++j) {
        float a = __builtin_nontemporal_load(g + (size_t)(2 * j) * DHWi + idx);
        float b = __builtin_nontemporal_load(g + (size_t)(2 * j + 1) * DHWi + idx);
        q[j] = pack_bf16(a, b);
    }
    uint2* o = (uint2*)(gt + (size_t)idx * 6);
    o[0] = make_uint2(q[0], q[1]);
    o[1] = make_uint2(q[2], q[3]);
    o[2] = make_uint2(q[4], q[5]);
}

__global__ __launch_bounds__(256) void trilerp_bf16(
    const float* __restrict__ xyz, const uint32_t* __restrict__ gt,
    const float* __restrict__ xyz_min, const float* __restrict__ xyz_max,
    float* __restrict__ out, int n) {
    int i = blockIdx.x * 256 + threadIdx.x;
    if (i >= n) return;

    float px = xyz[3 * (size_t)i + 0];
    float py = xyz[3 * (size_t)i + 1];
    float pz = xyz[3 * (size_t)i + 2];
    int d0, h0, w0; float fd, fh, fw;
    coord(px, xyz_min[0], xyz_max[0], d0, fd);
    coord(py, xyz_min[1], xyz_max[1], h0, fh);
    coord(pz, xyz_min[2], xyz_max[2], w0, fw);

    const uint32_t* base = gt + ((size_t)(d0 * HH + h0) * WW + w0) * 6;
    const int sD = HWi * 6;
    const int sH = WW * 6;

    float acc[12];
#pragma unroll
    for (int c = 0; c < 12; ++c) acc[c] = 0.0f;
    float wd[2] = {1.0f - fd, fd};
    float wh[2] = {1.0f - fh, fh};

#pragma unroll
    for (int dd = 0; dd < 2; ++dd) {
#pragma unroll
        for (int hh = 0; hh < 2; ++hh) {
            const uint2* p2 = (const uint2*)(base + dd * sD + hh * sH);
            uint2 a0 = p2[0], a1 = p2[1], a2 = p2[2];
            uint2 b0 = p2[3], b1 = p2[4], b2 = p2[5];
            float wdh = wd[dd] * wh[hh];
            uint32_t qa[6] = {a0.x, a0.y, a1.x, a1.y, a2.x, a2.y};
            uint32_t qb[6] = {b0.x, b0.y, b1.x, b1.y, b2.x, b2.y};
#pragma unroll
            for (int j = 0; j < 6; ++j) {
                float v0l = bf_lo(qa[j]), v0h = bf_hi(qa[j]);
                float v1l = bf_lo(qb[j]), v1h = bf_hi(qb[j]);
                float tl = fmaf(fw, v1l - v0l, v0l);
                float th = fmaf(fw, v1h - v0h, v0h);
                acc[2 * j]     = fmaf(wdh, tl, acc[2 * j]);
                acc[2 * j + 1] = fmaf(wdh, th, acc[2 * j + 1]);
            }
        }
    }

    float4* o = (float4*)(out + (size_t)i * 12);
    o[0] = make_float4(acc[0], acc[1], acc[2], acc[3]);
    o[1] = make_float4(acc[4], acc[5], acc[6], acc[7]);
    o[2] = make_float4(acc[8], acc[9], acc[10], acc[11]);
}

// ======================= Direct fallback (no workspace) =======================
__global__ __launch_bounds__(256) void trilerp_direct(
    const float* __restrict__ xyz, const float* __restrict__ g,
    const float* __restrict__ xyz_min, const float* __restrict__ xyz_max,
    float* __restrict__ out, int n) {
    int i = blockIdx.x * 256 + threadIdx.x;
    if (i >= n) return;
    float px = xyz[3 * (size_t)i + 0];
    float py = xyz[3 * (size_t)i + 1];
    float pz = xyz[3 * (size_t)i + 2];
    int d0, h0, w0; float fd, fh, fw;
    coord(px, xyz_min[0], xyz_max[0], d0, fd);
    coord(py, xyz_min[1], xyz_max[1], h0, fh);
    coord(pz, xyz_min[2], xyz_max[2], w0, fw);

    size_t base = (size_t)(d0 * HH + h0) * WW + w0;
    float w00 = (1.0f - fd) * (1.0f - fh);
    float w01 = (1.0f - fd) * fh;
    float w10 = fd * (1.0f - fh);
    float w11 = fd * fh;
#pragma unroll
    for (int c = 0; c < CC; ++c) {
        const float* gc = g + (size_t)c * DHWi + base;
        float v000 = gc[0],        v001 = gc[1];
        float v010 = gc[WW],       v011 = gc[WW + 1];
        float v100 = gc[HWi],      v101 = gc[HWi + 1];
        float v110 = gc[HWi + WW], v111 = gc[HWi + WW + 1];
        float t00 = fmaf(fw, v001 - v000, v000);
        float t01 = fmaf(fw, v011 - v010, v010);
        float t10 = fmaf(fw, v101 - v100, v100);
        float t11 = fmaf(fw, v111 - v110, v110);
        out[(size_t)i * CC + c] = w00 * t00 + w01 * t01 + w10 * t10 + w11 * t11;
    }
}

extern "C" void kernel_launch(void* const* d_in, const int* in_sizes, int n_in,
                              void* d_out, int out_size, void* d_ws, size_t ws_size,
                              hipStream_t stream) {
    const float* xyz  = (const float*)d_in[0];
    const float* grid = (const float*)d_in[1];
    const float* mn   = (const float*)d_in[2];
    const float* mx   = (const float*)d_in[3];
    float* out = (float*)d_out;
    int n = in_sizes[0] / 3;

    if (ws_size >= GT32_BYTES) {
        uint4* gt = (uint4*)d_ws;
        transpose_pad32<<<DHWi / 256, 256, 0, stream>>>(grid, gt);
        trilerp_pad32<<<(n + 255) / 256, 256, 0, stream>>>(xyz, gt, mn, mx, out, n);
    } else if (ws_size >= GT24_BYTES) {
        uint32_t* gt = (uint32_t*)d_ws;
        transpose_to_bf16<<<DHWi / 256, 256, 0, stream>>>(grid, gt);
        trilerp_bf16<<<(n + 255) / 256, 256, 0, stream>>>(xyz, gt, mn, mx, out, n);
    } else {
        trilerp_direct<<<(n + 255) / 256, 256, 0, stream>>>(xyz, grid, mn, mx, out, n);
    }
}

// Round 5
// 268.057 us; speedup vs baseline: 2.0964x; 2.0964x over previous
//
#include <hip/hip_runtime.h>
#include <stdint.h>

// Problem constants: grid (1, C=12, D=160, H=160, W=160), N = 2e6 points.
#define CC 12
#define DD 160
#define HH 160
#define WW 160

static constexpr int    HWi   = HH * WW;          // 25600
static constexpr int    DHWi  = DD * HH * WW;     // 4,096,000
static constexpr int    D2    = DD / 2;           // 80
static constexpr int    H2    = HH / 2;           // 80
static constexpr int    NG    = D2 * H2 * WW;     // 1,024,000 groups (96B each)
static constexpr size_t ILV_BYTES  = (size_t)NG * 96;    // 98,304,000 (bf16, dh-interleaved)
static constexpr size_t GT24_BYTES = (size_t)DHWi * 24;  // 98,304,000 (bf16 DHWC fallback)

typedef float f32x4 __attribute__((ext_vector_type(4)));

// ---- bf16 helpers (RNE) ----
__device__ __forceinline__ uint32_t pack_bf16(float a, float b) {
    uint32_t ua = __float_as_uint(a);
    uint32_t ub = __float_as_uint(b);
    uint32_t ra = (ua + 0x7fffu + ((ua >> 16) & 1u)) >> 16;
    uint32_t rb = (ub + 0x7fffu + ((ub >> 16) & 1u)) >> 16;
    return (ra & 0xffffu) | (rb << 16);
}
__device__ __forceinline__ float bf_lo(uint32_t q) { return __uint_as_float(q << 16); }
__device__ __forceinline__ float bf_hi(uint32_t q) { return __uint_as_float(q & 0xffff0000u); }

// u = clip((p-min)/(max-min)*(size-1)), i0 = clip(floor(u), 0, size-2), f = u - i0
__device__ __forceinline__ void coord(float p, float mn, float mx, int& i0, float& f) {
    float u = (p - mn) / (mx - mn) * 159.0f;
    u = fminf(fmaxf(u, 0.0f), 159.0f);
    float i0f = fminf(floorf(u), 158.0f);
    f = u - i0f;
    i0 = (int)i0f;
}

// =============== Main path: (d,h)-parity interleaved bf16 layout ===============
// Group (d2,h2,w) = 96B: [dp][hp][c] -> byte offset dp*48 + hp*24 + c*2.
// Group byte address = ((d2*H2 + h2)*WW + w) * 96.  w is the fast axis (96B stride).
__global__ __launch_bounds__(256) void transpose_ileave(
    const float* __restrict__ g, uint32_t* __restrict__ gt) {
    int gi = blockIdx.x * 256 + threadIdx.x;
    if (gi >= NG) return;
    int w  = gi % WW;
    int t  = gi / WW;
    int h0 = (t % H2) * 2;
    int d0 = (t / H2) * 2;

    uint32_t q[24];
#pragma unroll
    for (int dp = 0; dp < 2; ++dp) {
#pragma unroll
        for (int hp = 0; hp < 2; ++hp) {
            size_t s = (size_t)(d0 + dp) * HWi + (size_t)(h0 + hp) * WW + w;
            int qb = (dp * 2 + hp) * 6;
#pragma unroll
            for (int cj = 0; cj < 6; ++cj) {
                float a = __builtin_nontemporal_load(g + (size_t)(2 * cj) * DHWi + s);
                float b = __builtin_nontemporal_load(g + (size_t)(2 * cj + 1) * DHWi + s);
                q[qb + cj] = pack_bf16(a, b);   // dword cj = channels 2cj (lo), 2cj+1 (hi)
            }
        }
    }
    uint4* o = (uint4*)(gt + (size_t)gi * 24);   // 96B, 16B-aligned (96 % 16 == 0)
#pragma unroll
    for (int k = 0; k < 6; ++k)
        o[k] = make_uint4(q[4 * k], q[4 * k + 1], q[4 * k + 2], q[4 * k + 3]);
}

__global__ __launch_bounds__(256, 4) void trilerp_ileave(
    const float* __restrict__ xyz, const uint32_t* __restrict__ gt,
    const float* __restrict__ xyz_min, const float* __restrict__ xyz_max,
    float* __restrict__ out, int n) {
    int i = blockIdx.x * 256 + threadIdx.x;
    if (i >= n) return;

    float px = __builtin_nontemporal_load(xyz + 3 * (size_t)i + 0);
    float py = __builtin_nontemporal_load(xyz + 3 * (size_t)i + 1);
    float pz = __builtin_nontemporal_load(xyz + 3 * (size_t)i + 2);

    int d0, h0, w0; float fd, fh, fw;
    coord(px, xyz_min[0], xyz_max[0], d0, fd);
    coord(py, xyz_min[1], xyz_max[1], h0, fh);
    coord(pz, xyz_min[2], xyz_max[2], w0, fw);

    // Issue all 24 gather loads (4 corner-combos x 2 w-cells x 3 uint2), then compute.
    uint2 s0[4][3], s1[4][3];
#pragma unroll
    for (int dd = 0; dd < 2; ++dd) {
#pragma unroll
        for (int hh = 0; hh < 2; ++hh) {
            int dc = d0 + dd, hc = h0 + hh;
            int d2 = dc >> 1, dp = dc & 1;
            int h2 = hc >> 1, hp = hc & 1;
            size_t gi = ((size_t)(d2 * H2 + h2)) * WW + w0;
            const uint2* p = (const uint2*)gt + gi * 12 + (dp * 2 + hp) * 3;
            int k = dd * 2 + hh;
            s0[k][0] = p[0];  s0[k][1] = p[1];  s0[k][2] = p[2];    // w0 cell (24B)
            s1[k][0] = p[12]; s1[k][1] = p[13]; s1[k][2] = p[14];   // w1 cell (+96B)
        }
    }

    float acc[12];
#pragma unroll
    for (int c = 0; c < 12; ++c) acc[c] = 0.0f;
    float wd[2] = {1.0f - fd, fd};
    float wh[2] = {1.0f - fh, fh};

#pragma unroll
    for (int dd = 0; dd < 2; ++dd) {
#pragma unroll
        for (int hh = 0; hh < 2; ++hh) {
            int k = dd * 2 + hh;
            float wdh = wd[dd] * wh[hh];
            uint32_t qa[6] = {s0[k][0].x, s0[k][0].y, s0[k][1].x, s0[k][1].y, s0[k][2].x, s0[k][2].y};
            uint32_t qb[6] = {s1[k][0].x, s1[k][0].y, s1[k][1].x, s1[k][1].y, s1[k][2].x, s1[k][2].y};
#pragma unroll
            for (int j = 0; j < 6; ++j) {
                float v0l = bf_lo(qa[j]), v0h = bf_hi(qa[j]);
                float v1l = bf_lo(qb[j]), v1h = bf_hi(qb[j]);
                float tl = fmaf(fw, v1l - v0l, v0l);
                float th = fmaf(fw, v1h - v0h, v0h);
                acc[2 * j]     = fmaf(wdh, tl, acc[2 * j]);
                acc[2 * j + 1] = fmaf(wdh, th, acc[2 * j + 1]);
            }
        }
    }

    float* o = out + (size_t)i * 12;
    f32x4 o0 = {acc[0], acc[1], acc[2],  acc[3]};
    f32x4 o1 = {acc[4], acc[5], acc[6],  acc[7]};
    f32x4 o2 = {acc[8], acc[9], acc[10], acc[11]};
    __builtin_nontemporal_store(o0, (f32x4*)(o + 0));
    __builtin_nontemporal_store(o1, (f32x4*)(o + 4));
    __builtin_nontemporal_store(o2, (f32x4*)(o + 8));
}

// ======================= 24B DHWC fallback (round-1 kernel) =======================
__global__ __launch_bounds__(256) void transpose_to_bf16(
    const float* __restrict__ g, uint32_t* __restrict__ gt) {
    int idx = blockIdx.x * 256 + threadIdx.x;
    if (idx >= DHWi) return;
    uint32_t q[6];
#pragma unroll
    for (int j = 0; j < 6; ++j) {
        float a = __builtin_nontemporal_load(g + (size_t)(2 * j) * DHWi + idx);
        float b = __builtin_nontemporal_load(g + (size_t)(2 * j + 1) * DHWi + idx);
        q[j] = pack_bf16(a, b);
    }
    uint2* o = (uint2*)(gt + (size_t)idx * 6);
    o[0] = make_uint2(q[0], q[1]);
    o[1] = make_uint2(q[2], q[3]);
    o[2] = make_uint2(q[4], q[5]);
}

__global__ __launch_bounds__(256) void trilerp_bf16(
    const float* __restrict__ xyz, const uint32_t* __restrict__ gt,
    const float* __restrict__ xyz_min, const float* __restrict__ xyz_max,
    float* __restrict__ out, int n) {
    int i = blockIdx.x * 256 + threadIdx.x;
    if (i >= n) return;
    float px = xyz[3 * (size_t)i + 0];
    float py = xyz[3 * (size_t)i + 1];
    float pz = xyz[3 * (size_t)i + 2];
    int d0, h0, w0; float fd, fh, fw;
    coord(px, xyz_min[0], xyz_max[0], d0, fd);
    coord(py, xyz_min[1], xyz_max[1], h0, fh);
    coord(pz, xyz_min[2], xyz_max[2], w0, fw);

    const uint32_t* base = gt + ((size_t)(d0 * HH + h0) * WW + w0) * 6;
    const int sD = HWi * 6;
    const int sH = WW * 6;

    float acc[12];
#pragma unroll
    for (int c = 0; c < 12; ++c) acc[c] = 0.0f;
    float wd[2] = {1.0f - fd, fd};
    float wh[2] = {1.0f - fh, fh};

#pragma unroll
    for (int dd = 0; dd < 2; ++dd) {
#pragma unroll
        for (int hh = 0; hh < 2; ++hh) {
            const uint2* p2 = (const uint2*)(base + dd * sD + hh * sH);
            uint2 a0 = p2[0], a1 = p2[1], a2 = p2[2];
            uint2 b0 = p2[3], b1 = p2[4], b2 = p2[5];
            float wdh = wd[dd] * wh[hh];
            uint32_t qa[6] = {a0.x, a0.y, a1.x, a1.y, a2.x, a2.y};
            uint32_t qb[6] = {b0.x, b0.y, b1.x, b1.y, b2.x, b2.y};
#pragma unroll
            for (int j = 0; j < 6; ++j) {
                float v0l = bf_lo(qa[j]), v0h = bf_hi(qa[j]);
                float v1l = bf_lo(qb[j]), v1h = bf_hi(qb[j]);
                float tl = fmaf(fw, v1l - v0l, v0l);
                float th = fmaf(fw, v1h - v0h, v0h);
                acc[2 * j]     = fmaf(wdh, tl, acc[2 * j]);
                acc[2 * j + 1] = fmaf(wdh, th, acc[2 * j + 1]);
            }
        }
    }

    float4* o = (float4*)(out + (size_t)i * 12);
    o[0] = make_float4(acc[0], acc[1], acc[2], acc[3]);
    o[1] = make_float4(acc[4], acc[5], acc[6], acc[7]);
    o[2] = make_float4(acc[8], acc[9], acc[10], acc[11]);
}

// ======================= Direct fallback (no workspace) =======================
__global__ __launch_bounds__(256) void trilerp_direct(
    const float* __restrict__ xyz, const float* __restrict__ g,
    const float* __restrict__ xyz_min, const float* __restrict__ xyz_max,
    float* __restrict__ out, int n) {
    int i = blockIdx.x * 256 + threadIdx.x;
    if (i >= n) return;
    float px = xyz[3 * (size_t)i + 0];
    float py = xyz[3 * (size_t)i + 1];
    float pz = xyz[3 * (size_t)i + 2];
    int d0, h0, w0; float fd, fh, fw;
    coord(px, xyz_min[0], xyz_max[0], d0, fd);
    coord(py, xyz_min[1], xyz_max[1], h0, fh);
    coord(pz, xyz_min[2], xyz_max[2], w0, fw);

    size_t base = (size_t)(d0 * HH + h0) * WW + w0;
    float w00 = (1.0f - fd) * (1.0f - fh);
    float w01 = (1.0f - fd) * fh;
    float w10 = fd * (1.0f - fh);
    float w11 = fd * fh;
#pragma unroll
    for (int c = 0; c < CC; ++c) {
        const float* gc = g + (size_t)c * DHWi + base;
        float v000 = gc[0],        v001 = gc[1];
        float v010 = gc[WW],       v011 = gc[WW + 1];
        float v100 = gc[HWi],      v101 = gc[HWi + 1];
        float v110 = gc[HWi + WW], v111 = gc[HWi + WW + 1];
        float t00 = fmaf(fw, v001 - v000, v000);
        float t01 = fmaf(fw, v011 - v010, v010);
        float t10 = fmaf(fw, v101 - v100, v100);
        float t11 = fmaf(fw, v111 - v110, v110);
        out[(size_t)i * CC + c] = w00 * t00 + w01 * t01 + w10 * t10 + w11 * t11;
    }
}

extern "C" void kernel_launch(void* const* d_in, const int* in_sizes, int n_in,
                              void* d_out, int out_size, void* d_ws, size_t ws_size,
                              hipStream_t stream) {
    const float* xyz  = (const float*)d_in[0];
    const float* grid = (const float*)d_in[1];
    const float* mn   = (const float*)d_in[2];
    const float* mx   = (const float*)d_in[3];
    float* out = (float*)d_out;
    int n = in_sizes[0] / 3;

    if (ws_size >= ILV_BYTES) {
        uint32_t* gt = (uint32_t*)d_ws;
        transpose_ileave<<<NG / 256, 256, 0, stream>>>(grid, gt);
        trilerp_ileave<<<(n + 255) / 256, 256, 0, stream>>>(xyz, gt, mn, mx, out, n);
    } else if (ws_size >= GT24_BYTES) {
        uint32_t* gt = (uint32_t*)d_ws;
        transpose_to_bf16<<<DHWi / 256, 256, 0, stream>>>(grid, gt);
        trilerp_bf16<<<(n + 255) / 256, 256, 0, stream>>>(xyz, gt, mn, mx, out, n);
    } else {
        trilerp_direct<<<(n + 255) / 256, 256, 0, stream>>>(xyz, grid, mn, mx, out, n);
    }
}